// Round 1
// baseline (2706.075 us; speedup 1.0000x reference)
//
#include <hip/hip_runtime.h>
#include <stdint.h>

#define D_EMB 512
#define D_DEC 1024
#define VOCAB 32000
#define BATCH 64
#define STEPS 64

// Workspace layout (all in d_ws; re-poisoned 0xAA before every timed call,
// so everything here is (re)initialized by the kernels each call).
struct Ws {
    float h[2][D_DEC];                 // ping-pong GRU state (B=1: all batch rows identical)
    float logits[VOCAB];               // logits of current step (B=1)
    unsigned long long slot[STEPS];    // per-step argmax accumulator (packed key|~idx)
};

// Monotone map: float order -> unsigned order; low word = ~idx so that
// atomicMax tie-breaks toward the SMALLEST index (numpy argmax rule).
__device__ __forceinline__ unsigned long long pack_lv(float f, int v) {
    unsigned u = __float_as_uint(f);
    unsigned key = (u & 0x80000000u) ? ~u : (u | 0x80000000u);
    return ((unsigned long long)key << 32) | (unsigned)(0xFFFFFFFFu - (unsigned)v);
}
__device__ __forceinline__ int unpack_v(unsigned long long p) {
    return (int)(0xFFFFFFFFu - (unsigned)(p & 0xFFFFFFFFu));
}

// K1: (a) broadcast step t-1 logits/preds to all 64 batch rows of d_out,
//     (b) GRU cell for step t (wave-per-output-element, 1024 waves).
// At t==0: zero the argmax slots instead of broadcasting. At t==STEPS: broadcast only.
__global__ __launch_bounds__(256) void k_gates(
    const float* __restrict__ embs, const float* __restrict__ init,
    const float* __restrict__ w_ih, const float* __restrict__ w_hh,
    const float* __restrict__ b_ih, const float* __restrict__ b_hh,
    const int* __restrict__ bos_idx,
    float* __restrict__ out_logits, float* __restrict__ out_preds,
    Ws* __restrict__ ws, int t)
{
    const int lane = threadIdx.x & 63;
    const int gtid = blockIdx.x * blockDim.x + threadIdx.x;
    const int nthr = gridDim.x * blockDim.x;
    const int wid  = gtid >> 6;   // 0..1023 with grid 256x256

    int pred_prev;
    if (t == 0) pred_prev = *bos_idx;
    else        pred_prev = unpack_v(ws->slot[t - 1]);

    if (t > 0) {
        // Broadcast logits(t-1) (128 KB, L2-hot) to all 64 batch rows; coalesced float4 stores.
        const float4* lb = (const float4*)ws->logits;        // 8000 float4
        float4* ob = (float4*)out_logits;
        const int VQ = VOCAB / 4;                            // 8000
        for (int idx = gtid; idx < BATCH * VQ; idx += nthr) {
            int b = idx / VQ;
            int c = idx - b * VQ;
            ob[(size_t)b * (STEPS * (size_t)VQ) + (size_t)(t - 1) * VQ + c] = lb[c];
        }
        if (gtid < BATCH) out_preds[gtid * STEPS + (t - 1)] = (float)pred_prev;
    } else {
        if (gtid < STEPS) ws->slot[gtid] = 0ull;   // below any real packed logit
    }

    if (t >= STEPS) return;    // final launch: broadcast only

    // ---- GRU cell, wave-per-j ----
    const int j = wid;
    if (j >= D_DEC) return;

    const float* hprev = (t == 0) ? init : ws->h[(t + 1) & 1];
    const float* x     = embs + (size_t)pred_prev * D_EMB;

    const float4* x4   = (const float4*)x;       // 128 float4
    const float4* h4   = (const float4*)hprev;   // 256 float4
    const float4* wih4 = (const float4*)w_ih;    // row = 128 float4
    const float4* whh4 = (const float4*)w_hh;    // row = 256 float4

    float s_ir = 0.f, s_iz = 0.f, s_in = 0.f;
    float s_hr = 0.f, s_hz = 0.f, s_hn = 0.f;

    #pragma unroll
    for (int k0 = 0; k0 < 2; ++k0) {
        int k = k0 * 64 + lane;
        float4 xv = x4[k];
        float4 a = wih4[(size_t)j * 128 + k];
        float4 b = wih4[(size_t)(j + D_DEC) * 128 + k];
        float4 c = wih4[(size_t)(j + 2 * D_DEC) * 128 + k];
        s_ir += a.x * xv.x + a.y * xv.y + a.z * xv.z + a.w * xv.w;
        s_iz += b.x * xv.x + b.y * xv.y + b.z * xv.z + b.w * xv.w;
        s_in += c.x * xv.x + c.y * xv.y + c.z * xv.z + c.w * xv.w;
    }
    #pragma unroll
    for (int k0 = 0; k0 < 4; ++k0) {
        int k = k0 * 64 + lane;
        float4 hv = h4[k];
        float4 a = whh4[(size_t)j * 256 + k];
        float4 b = whh4[(size_t)(j + D_DEC) * 256 + k];
        float4 c = whh4[(size_t)(j + 2 * D_DEC) * 256 + k];
        s_hr += a.x * hv.x + a.y * hv.y + a.z * hv.z + a.w * hv.w;
        s_hz += b.x * hv.x + b.y * hv.y + b.z * hv.z + b.w * hv.w;
        s_hn += c.x * hv.x + c.y * hv.y + c.z * hv.z + c.w * hv.w;
    }

    #pragma unroll
    for (int off = 32; off > 0; off >>= 1) {
        s_ir += __shfl_down(s_ir, off, 64);
        s_iz += __shfl_down(s_iz, off, 64);
        s_in += __shfl_down(s_in, off, 64);
        s_hr += __shfl_down(s_hr, off, 64);
        s_hz += __shfl_down(s_hz, off, 64);
        s_hn += __shfl_down(s_hn, off, 64);
    }

    if (lane == 0) {
        float ir = s_ir + b_ih[j];
        float iz = s_iz + b_ih[j + D_DEC];
        float in_ = s_in + b_ih[j + 2 * D_DEC];
        float hr = s_hr + b_hh[j];
        float hz = s_hz + b_hh[j + D_DEC];
        float hn = s_hn + b_hh[j + 2 * D_DEC];
        float r = 1.f / (1.f + expf(-(ir + hr)));
        float z = 1.f / (1.f + expf(-(iz + hz)));
        float n = tanhf(in_ + r * hn);
        ws->h[t & 1][j] = (1.f - z) * n + z * hprev[j];
    }
}

// K2: logits GEMV (32000 x 1024) for step t from ws->h[t&1] + argmax.
// Wave-per-row strided; h cached in registers; one u64 atomicMax per block.
__global__ __launch_bounds__(256) void k_logits(
    const float* __restrict__ W_out, const float* __restrict__ b_out,
    Ws* __restrict__ ws, int t)
{
    const int lane = threadIdx.x & 63;
    const int widx = threadIdx.x >> 6;              // 0..3
    const int wid  = blockIdx.x * 4 + widx;
    const int nw   = gridDim.x * 4;

    const float4* h4 = (const float4*)ws->h[t & 1]; // 256 float4
    float4 hr[4];
    #pragma unroll
    for (int k = 0; k < 4; ++k) hr[k] = h4[k * 64 + lane];

    const float4* W4 = (const float4*)W_out;        // row = 256 float4
    unsigned long long best = 0ull;

    for (int v = wid; v < VOCAB; v += nw) {
        const float4* row = W4 + (size_t)v * 256;
        float s = 0.f;
        #pragma unroll
        for (int k = 0; k < 4; ++k) {
            float4 w = row[k * 64 + lane];
            s += w.x * hr[k].x + w.y * hr[k].y + w.z * hr[k].z + w.w * hr[k].w;
        }
        #pragma unroll
        for (int off = 32; off > 0; off >>= 1) s += __shfl_down(s, off, 64);
        if (lane == 0) {
            float logit = s + b_out[v];
            ws->logits[v] = logit;
            unsigned long long p = pack_lv(logit, v);
            if (p > best) best = p;
        }
    }

    __shared__ unsigned long long sb[4];
    if (lane == 0) sb[widx] = best;
    __syncthreads();
    if (threadIdx.x == 0) {
        unsigned long long b = sb[0];
        #pragma unroll
        for (int i = 1; i < 4; ++i) if (sb[i] > b) b = sb[i];
        atomicMax(&ws->slot[t], b);
    }
}

extern "C" void kernel_launch(void* const* d_in, const int* in_sizes, int n_in,
                              void* d_out, int out_size, void* d_ws, size_t ws_size,
                              hipStream_t stream) {
    const float* embs  = (const float*)d_in[0];
    const float* init  = (const float*)d_in[1];
    const float* w_ih  = (const float*)d_in[2];
    const float* w_hh  = (const float*)d_in[3];
    const float* b_ih  = (const float*)d_in[4];
    const float* b_hh  = (const float*)d_in[5];
    const float* W_out = (const float*)d_in[6];
    const float* b_out = (const float*)d_in[7];
    const int*   bos   = (const int*)d_in[8];

    float* out_logits = (float*)d_out;                                   // [B, T, V]
    float* out_preds  = out_logits + (size_t)BATCH * STEPS * VOCAB;      // [B, T] as float

    Ws* ws = (Ws*)d_ws;

    for (int t = 0; t <= STEPS; ++t) {
        hipLaunchKernelGGL(k_gates, dim3(256), dim3(256), 0, stream,
                           embs, init, w_ih, w_hh, b_ih, b_hh, bos,
                           out_logits, out_preds, ws, t);
        if (t < STEPS) {
            hipLaunchKernelGGL(k_logits, dim3(512), dim3(256), 0, stream,
                               W_out, b_out, ws, t);
        }
    }
}